// Round 9
// baseline (1279.397 us; speedup 1.0000x reference)
//
#include <hip/hip_runtime.h>

// ---------------------------------------------------------------------------
// RNN-KAN forward.  B=1024, Tx=64, IN0=256, H=512, TY=16, coeff=8.
// Output: y_pred (1024*16 f32) then h_all (1024*80*512 f32), flat.
// ---------------------------------------------------------------------------

using s16x8 = __attribute__((ext_vector_type(8))) short;
using u16x8 = __attribute__((ext_vector_type(8))) unsigned short;
using f32x4 = __attribute__((ext_vector_type(4))) float;
using u32x2 = __attribute__((ext_vector_type(2))) unsigned;

#define HALL_TSTRIDE 512
#define HALL_BSTRIDE (80 * 512)

__device__ __forceinline__ unsigned short f2bf(float f) {
  unsigned u = __builtin_bit_cast(unsigned, f);
  u += 0x7fffu + ((u >> 16) & 1u);   // round-to-nearest-even
  return (unsigned short)(u >> 16);
}
__device__ __forceinline__ float bf2f(unsigned short h) {
  unsigned u = ((unsigned)h) << 16;
  return __builtin_bit_cast(float, u);
}
__device__ __forceinline__ float silu(float x) {
  return x / (1.f + __expf(-x));
}
__device__ __forceinline__ float tanh_fast(float x) {
  float e2 = __expf(2.f * x);                    // inf/0 saturate correctly
  return 1.f - 2.f * __builtin_amdgcn_rcpf(e2 + 1.f);
}

// 8 cubic B-spline basis values on the uniform 12-knot grid.
__device__ __forceinline__ void basis8_f32(float xv, float g0, float invh, float* out) {
  float u = (xv - g0) * invh;
  float fs = floorf(u);
  int s = (int)fs;
  float r = u - fs;
  float omr = 1.f - r;
  float r2 = r * r, r3 = r2 * r;
  float n0 = (1.f / 6.f) * omr * omr * omr;
  float n1 = (1.f / 6.f) * (3.f * r3 - 6.f * r2 + 4.f);
  float n2 = (1.f / 6.f) * (-3.f * r3 + 3.f * r2 + 3.f * r + 1.f);
  float n3 = (1.f / 6.f) * r3;
#pragma unroll
  for (int j = 0; j < 8; ++j) {
    int d = s - j;
    out[j] = (d == 0) ? n3 : (d == 1) ? n2 : (d == 2) ? n1 : (d == 3) ? n0 : 0.f;
  }
}

__device__ __forceinline__ u16x8 basis8_bf16(float xv, float g0, float invh) {
  float t[8];
  basis8_f32(xv, g0, invh, t);
  u16x8 o;
#pragma unroll
  for (int j = 0; j < 8; ++j) o[j] = f2bf(t[j]);
  return o;
}

// ---------------------------------------------------------------------------
// Prep kernels
// ---------------------------------------------------------------------------
// Waug2: tiled + swizzled B-panel image for global_load_lds.
// Region per kstep ks (64 k): 512 rows x 64 shorts (128 B/row = 8 slots of 16B).
// Logical slot q = (k>>3)&7 stored at physical slot p = q ^ (o&7).
__global__ __launch_bounds__(256) void prep_waug2(const float* __restrict__ bw,
                                                  const float* __restrict__ sw,
                                                  const float* __restrict__ sc,
                                                  unsigned short* __restrict__ Waug2) {
  int o = blockIdx.x;
  for (int k = threadIdx.x; k < 2304; k += 256) {
    float v;
    if (k < 256) {
      v = bw[o * 256 + k];
    } else {
      int idx = k - 256;
      int i = idx >> 3, g = idx & 7;
      v = sw[(o * 256 + i) * 8 + g] * sc[o * 256 + i];
    }
    int ks = k >> 6;
    int q = (k >> 3) & 7;
    int p = q ^ (o & 7);
    int e = k & 7;
    Waug2[(long)ks * 32768 + o * 64 + p * 8 + e] = f2bf(v);
  }
}

__global__ __launch_bounds__(256) void prep_whh(const float* __restrict__ w,
                                                unsigned short* __restrict__ hi,
                                                unsigned short* __restrict__ lo) {
  for (int i = blockIdx.x * 256 + threadIdx.x; i < 512 * 512; i += gridDim.x * 256) {
    float v = w[i];
    unsigned short h = f2bf(v);
    hi[i] = h;
    lo[i] = f2bf(v - bf2f(h));
  }
}

// i2h for x==0: PARALLEL version (R8's was 2-block serial, latency-bound —
// 512 threads each doing 256 dependent uncoalesced reads).  One block per
// output o; thread i handles input i (32 B coalesced); LDS tree reduce.
// Also zeroes the sync counters (block 0).
__global__ __launch_bounds__(256) void prep_i2hz(const float* __restrict__ sw,
                                                 const float* __restrict__ sc,
                                                 const float* __restrict__ grd,
                                                 float* __restrict__ i2hz,
                                                 unsigned* __restrict__ cnt) {
  __shared__ float red[256];
  const int o = blockIdx.x;
  const int t = threadIdx.x;
  if (o == 0) {
    for (int i = t; i < 64 * 32; i += 256) cnt[i] = 0u;
  }
  float g0 = grd[0];
  float invh = 1.f / (grd[1] - grd[0]);
  float bs[8];
  basis8_f32(0.f, g0, invh, bs);
  const float* swrow = sw + ((long)o * 256 + t) * 8;
  float a = 0.f;
#pragma unroll
  for (int j = 0; j < 8; ++j) a += bs[j] * swrow[j];
  red[t] = a * sc[o * 256 + t];
  __syncthreads();
  for (int w = 128; w > 0; w >>= 1) {
    if (t < w) red[t] += red[t + w];
    __syncthreads();
  }
  if (t == 0) i2hz[o] = red[0];
}

// ---------------------------------------------------------------------------
// Phase A: i2h GEMM.  C(65536 x 512) = A_aug(65536 x 2304) @ W_aug^T.
// 512 blocks x 512 threads; tile 128m x 512n (full N: A computed ONCE).
// B staged via global_load_lds(16) from pre-swizzled Waug2; A computed on
// the fly, swizzle-written.  8 waves 2x4, per-wave 64m x 128n.
// ---------------------------------------------------------------------------
__global__ __launch_bounds__(512, 2) void kan_i2h_gemm(const float* __restrict__ x,
                                                       const float* __restrict__ grd,
                                                       const unsigned short* __restrict__ Waug2,
                                                       float* __restrict__ hall) {
  __shared__ __align__(128) short Bs[512 * 64];   // 64 KB
  __shared__ __align__(128) short As[128 * 64];   // 16 KB

  const int m0 = blockIdx.x * 128;
  const int tid = threadIdx.x;
  const int lane = tid & 63, wave = tid >> 6;   // 8 waves
  const int wr = wave >> 2, wc = wave & 3;      // 2 x 4
  const int colg = lane & 15, kgrp = lane >> 4;

  float g0 = grd[0];
  float invh = 1.f / (grd[1] - grd[0]);

  f32x4 acc[4][8] = {};

  const int arow = tid >> 2, apart = tid & 3;   // A: 128 rows x 4 parts x 16k
  const float* xrow = x + (long)(m0 + arow) * 256;
  const int aswz = arow & 7;

  for (int ks = 0; ks < 36; ++ks) {
    // ---- B DMA: 64 KB linear copy (content pre-swizzled in Waug2) ----
    {
      const unsigned short* bsrc = Waug2 + (long)ks * 32768 + wave * 512 + lane * 8;
      char* bdst = (char*)Bs + wave * 1024;
#pragma unroll
      for (int i = 0; i < 8; ++i)
        __builtin_amdgcn_global_load_lds(
            (const __attribute__((address_space(1))) unsigned int*)(bsrc + i * 4096),
            (__attribute__((address_space(3))) unsigned int*)(bdst + i * 8192), 16, 0, 0);
    }
    // ---- A compute (16 k per thread) -> swizzled ds_write ----
    {
      int kA = ks * 64 + apart * 16;
      u16x8 d0, d1;
      if (ks < 4) {
        const float* xs = xrow + kA;
        f32x4 v0 = *(const f32x4*)(xs);
        f32x4 v1 = *(const f32x4*)(xs + 4);
        f32x4 v2 = *(const f32x4*)(xs + 8);
        f32x4 v3 = *(const f32x4*)(xs + 12);
#pragma unroll
        for (int e = 0; e < 4; ++e) {
          d0[e] = f2bf(silu(v0[e]));
          d0[e + 4] = f2bf(silu(v1[e]));
          d1[e] = f2bf(silu(v2[e]));
          d1[e + 4] = f2bf(silu(v3[e]));
        }
      } else {
        int i0 = (kA - 256) >> 3;
        d0 = basis8_bf16(xrow[i0], g0, invh);
        d1 = basis8_bf16(xrow[i0 + 1], g0, invh);
      }
      int p0 = (apart * 2) ^ aswz;
      int p1 = (apart * 2 + 1) ^ aswz;
      *(u16x8*)((char*)As + arow * 128 + p0 * 16) = d0;
      *(u16x8*)((char*)As + arow * 128 + p1 * 16) = d1;
    }
    __syncthreads();   // drains gload_lds (vmcnt) + ds_write (lgkm)
#pragma unroll
    for (int kk = 0; kk < 2; ++kk) {
      const int q = kk * 4 + kgrp;
      s16x8 a[4], b[8];
#pragma unroll
      for (int i = 0; i < 4; ++i) {
        int ra = wr * 64 + i * 16 + colg;
        a[i] = *(const s16x8*)((const char*)As + ra * 128 + (q ^ (ra & 7)) * 16);
      }
#pragma unroll
      for (int j = 0; j < 8; ++j) {
        int rb = wc * 128 + j * 16 + colg;
        b[j] = *(const s16x8*)((const char*)Bs + rb * 128 + (q ^ (rb & 7)) * 16);
      }
#pragma unroll
      for (int i = 0; i < 4; ++i)
#pragma unroll
        for (int j = 0; j < 8; ++j)
          acc[i][j] = __builtin_amdgcn_mfma_f32_16x16x32_bf16(a[i], b[j], acc[i][j], 0, 0, 0);
    }
    __syncthreads();
  }

  const int c0 = wc * 128;
#pragma unroll
  for (int i = 0; i < 4; ++i) {
    int mbase = m0 + wr * 64 + i * 16 + (kgrp << 2);
#pragma unroll
    for (int r = 0; r < 4; ++r) {
      int m = mbase + r;
      int bb = m >> 6, tt = m & 63;
      float* orow = hall + (long)bb * HALL_BSTRIDE + (long)tt * HALL_TSTRIDE + c0;
#pragma unroll
      for (int j = 0; j < 8; ++j) orow[j * 16 + colg] = acc[i][j][r];
    }
  }
}

// ---------------------------------------------------------------------------
// Phase B: VGPR-pinned-weight recurrence, 4-WAVE BLOCKS for latency overlap.
// 512 blocks x 256 threads = 2 blocks/CU (LDS 2x32KB=64/160, 8 waves/CU,
// VGPR capped 256 by launch_bounds -> co-residency has wide slack, unlike
// the R5 exact-packing deadlock).  Block = 16 batch rows x 64 cols (4 waves
// x 16 cols).  Per-wave work is IDENTICAL to R6/R8 (128 pinned weight VGPRs,
// same LDS h layout/reads, same 3-chain MFMA); the two independent blocks
// per CU interleave: one block's exchange spin / vmcnt stall hides under the
// other's MFMA+LDS phase.  Group = 8 col-sibling blocks on one XCD.
// Exchange protocol unchanged (proven): sc0sc1 stores into hall, release-
// atomic + relaxed spin (never acquire -> no buffer_inv), sc0sc1 refill.
// ---------------------------------------------------------------------------
__device__ __forceinline__ void pack_write_h(f32x4 v, int rr, int c16,
                                             char* hHb, char* hLb) {
  unsigned h0 = f2bf(v[0]), h1 = f2bf(v[1]), h2 = f2bf(v[2]), h3 = f2bf(v[3]);
  unsigned l0 = f2bf(v[0] - bf2f((unsigned short)h0));
  unsigned l1 = f2bf(v[1] - bf2f((unsigned short)h1));
  unsigned l2 = f2bf(v[2] - bf2f((unsigned short)h2));
  unsigned l3 = f2bf(v[3] - bf2f((unsigned short)h3));
  u32x2 hw, lw;
  hw[0] = h0 | (h1 << 16); hw[1] = h2 | (h3 << 16);
  lw[0] = l0 | (l1 << 16); lw[1] = l2 | (l3 << 16);
  int byte = (rr * 1024 + c16 * 8) ^ ((rr & 7) << 4);
  *(u32x2*)(hHb + byte) = hw;
  *(u32x2*)(hLb + byte) = lw;
}

__global__ __launch_bounds__(256, 2) void rnn_persist(
    const unsigned short* __restrict__ WhhHi,
    const unsigned short* __restrict__ WhhLo,
    const float* __restrict__ i2hz,
    const float* __restrict__ h2hb,
    const float* __restrict__ h0,
    float* __restrict__ hall,
    unsigned* __restrict__ cnt) {
  __shared__ __align__(16) char hHb[16 * 1024];
  __shared__ __align__(16) char hLb[16 * 1024];

  const int tid = threadIdx.x;
  const int lane = tid & 63;
  const int wave = tid >> 6;            // 0..3
  const int bid = blockIdx.x;
  // XCD-local grouping: the 8 col-siblings of a batch-group share bid%8
  const int xcd = bid & 7;              // XCD (round-robin dispatch)
  const int j = bid >> 3;               // 0..63
  const int cg = j & 7;                 // col-group 0..7
  const int g = xcd * 8 + (j >> 3);     // batch-group 0..63
  const int m0 = g * 16;                // batch rows
  const int colg = lane & 15;
  const int kgrp = lane >> 4;           // 0..3
  const int o = cg * 64 + wave * 16 + colg;    // this lane's output col
  const int aswz = (colg & 7) << 4;

  // ---- pin this wave's weight slice in VGPRs (asm: not rematerializable) --
  s16x8 wh[16], wl[16];
#pragma unroll
  for (int kk = 0; kk < 16; ++kk) {
    const unsigned short* ph = WhhHi + (long)o * 512 + kk * 32 + kgrp * 8;
    const unsigned short* pl = WhhLo + (long)o * 512 + kk * 32 + kgrp * 8;
    asm volatile("global_load_dwordx4 %0, %1, off" : "=v"(wh[kk]) : "v"(ph));
    asm volatile("global_load_dwordx4 %0, %1, off" : "=v"(wl[kk]) : "v"(pl));
  }
  const float bias = h2hb[o];
  const float i2z = i2hz[o];
  asm volatile("s_waitcnt vmcnt(0)" ::: "memory");
  __builtin_amdgcn_sched_barrier(0);

  // ---- prologue: h0 -> LDS (hi/lo, swizzled) ----
  {
    const int rr = tid >> 4, cc = tid & 15;
    const float* src = h0 + (long)(m0 + rr) * 512;
#pragma unroll
    for (int jj = 0; jj < 8; ++jj) {
      int c16 = cc + jj * 16;
      f32x4 v = *(const f32x4*)(src + c16 * 4);
      pack_write_h(v, rr, c16, hHb, hLb);
    }
  }
  __syncthreads();

  for (int T = 0; T < 80; ++T) {
    // issue i2h coherent loads early (land under MFMA loop)
    float i2v[4];
    if (T < 64) {
#pragma unroll
      for (int r = 0; r < 4; ++r) {
        const float* p = hall + (long)(m0 + kgrp * 4 + r) * HALL_BSTRIDE +
                         (long)T * HALL_TSTRIDE + o;
        asm volatile("global_load_dword %0, %1, off sc0 sc1" : "=v"(i2v[r]) : "v"(p));
      }
    }

    f32x4 aA = {}, aB = {}, aC = {};
#pragma unroll
    for (int kk = 0; kk < 16; ++kk) {
      int abyte = (colg * 1024 + kk * 64 + kgrp * 16) ^ aswz;
      s16x8 ah = *(const s16x8*)(hHb + abyte);
      s16x8 al = *(const s16x8*)(hLb + abyte);
      aA = __builtin_amdgcn_mfma_f32_16x16x32_bf16(ah, wh[kk], aA, 0, 0, 0);
      aB = __builtin_amdgcn_mfma_f32_16x16x32_bf16(ah, wl[kk], aB, 0, 0, 0);
      aC = __builtin_amdgcn_mfma_f32_16x16x32_bf16(al, wh[kk], aC, 0, 0, 0);
    }

    if (T < 64) {
      asm volatile("s_waitcnt vmcnt(0)" ::: "memory");
      __builtin_amdgcn_sched_barrier(0);
    } else {
#pragma unroll
      for (int r = 0; r < 4; ++r) i2v[r] = i2z;
    }

    // epilogue: tanh + coherent store of h into hall (the exchange medium)
#pragma unroll
    for (int r = 0; r < 4; ++r) {
      float pre = aA[r] + aB[r] + aC[r] + i2v[r] + bias;
      float h = tanh_fast(pre);
      float* p = hall + (long)(m0 + kgrp * 4 + r) * HALL_BSTRIDE +
                 (long)T * HALL_TSTRIDE + o;
      asm volatile("global_store_dword %0, %1, off sc0 sc1" :: "v"(p), "v"(h) : "memory");
    }

    if (T == 79) break;

    asm volatile("s_waitcnt vmcnt(0)" ::: "memory");
    __syncthreads();                       // all waves' stores complete
    if (tid == 0) {
      __hip_atomic_fetch_add(&cnt[g * 32], 1u, __ATOMIC_RELEASE,
                             __HIP_MEMORY_SCOPE_AGENT);
      unsigned tgt = 8u * (unsigned)(T + 1);
      while (__hip_atomic_load(&cnt[g * 32], __ATOMIC_RELAXED,
                               __HIP_MEMORY_SCOPE_AGENT) < tgt)
        __builtin_amdgcn_s_sleep(2);
    }
    __syncthreads();

    // A-refill: coherent loads of h_T (16 rows x 512) -> LDS hi/lo
    {
      const int rr = tid >> 4, cc = tid & 15;
      const float* src = hall + (long)(m0 + rr) * HALL_BSTRIDE + (long)T * HALL_TSTRIDE;
      f32x4 v[8];
#pragma unroll
      for (int jj = 0; jj < 8; ++jj) {
        const float* p = src + (cc + jj * 16) * 4;
        asm volatile("global_load_dwordx4 %0, %1, off sc0 sc1" : "=v"(v[jj]) : "v"(p));
      }
      asm volatile("s_waitcnt vmcnt(0)" ::: "memory");
      __builtin_amdgcn_sched_barrier(0);
#pragma unroll
      for (int jj = 0; jj < 8; ++jj) pack_write_h(v[jj], rr, cc + jj * 16, hHb, hLb);
    }
    __syncthreads();
  }
}

// ---------------------------------------------------------------------------
// y_pred[b][ty] = dot(h_all[b][64+ty][:], fc_w) + fc_b   (one wave per (b,ty))
// ---------------------------------------------------------------------------
__global__ __launch_bounds__(256) void y_final(const float* __restrict__ hall,
                                               const float* __restrict__ fcw,
                                               const float* __restrict__ fcb,
                                               float* __restrict__ y) {
  int gw = (blockIdx.x * 256 + threadIdx.x) >> 6;
  int lane = threadIdx.x & 63;
  int bb = gw >> 4, ty = gw & 15;
  const float* hrow = hall + (long)bb * HALL_BSTRIDE + (long)(64 + ty) * HALL_TSTRIDE;
  float s = 0.f;
#pragma unroll
  for (int c = 0; c < 8; ++c) s += hrow[lane + c * 64] * fcw[lane + c * 64];
#pragma unroll
  for (int off = 32; off > 0; off >>= 1) s += __shfl_xor(s, off);
  if (lane == 0) y[bb * 16 + ty] = s + fcb[0];
}

// ---------------------------------------------------------------------------
extern "C" void kernel_launch(void* const* d_in, const int* in_sizes, int n_in,
                              void* d_out, int out_size, void* d_ws, size_t ws_size,
                              hipStream_t stream) {
  (void)in_sizes; (void)n_in; (void)out_size; (void)ws_size;
  const float* x   = (const float*)d_in[0];
  const float* h0  = (const float*)d_in[1];
  const float* grd = (const float*)d_in[2];
  const float* bw  = (const float*)d_in[3];
  const float* sw  = (const float*)d_in[4];
  const float* sc  = (const float*)d_in[5];
  const float* whh = (const float*)d_in[6];
  const float* hbb = (const float*)d_in[7];
  const float* fcw = (const float*)d_in[8];
  const float* fcb = (const float*)d_in[9];

  float* out = (float*)d_out;
  float* ypred = out;
  float* hall = out + 1024 * 16;

  char* ws = (char*)d_ws;
  unsigned short* Waug2 = (unsigned short*)(ws);                 // 2359296 B
  unsigned short* WhhHi = (unsigned short*)(ws + 2359296);       // 524288 B
  unsigned short* WhhLo = (unsigned short*)(ws + 2883584);       // 524288 B
  float*          i2hz  = (float*)(ws + 3407872);                // 2048 B
  unsigned*       cnt   = (unsigned*)(ws + 3409920);             // 8192 B

  prep_waug2<<<512, 256, 0, stream>>>(bw, sw, sc, Waug2);
  prep_whh<<<512, 256, 0, stream>>>(whh, WhhHi, WhhLo);
  prep_i2hz<<<512, 256, 0, stream>>>(sw, sc, grd, i2hz, cnt);
  kan_i2h_gemm<<<512, 512, 0, stream>>>(x, grd, Waug2, hall);
  rnn_persist<<<512, 256, 0, stream>>>(WhhHi, WhhLo, i2hz, hbb, h0, hall, cnt);
  y_final<<<4096, 256, 0, stream>>>(hall, fcw, fcb, ypred);
}

// Round 10
// 712.619 us; speedup vs baseline: 1.7953x; 1.7953x over previous
//
#include <hip/hip_runtime.h>

// ---------------------------------------------------------------------------
// RNN-KAN forward.  B=1024, Tx=64, IN0=256, H=512, TY=16, coeff=8.
// Output: y_pred (1024*16 f32) then h_all (1024*80*512 f32), flat.
// R10 = R7 GEMM + R8-exact rnn_persist (400us proven) + R9 parallel i2hz.
// ---------------------------------------------------------------------------

using s16x8 = __attribute__((ext_vector_type(8))) short;
using u16x8 = __attribute__((ext_vector_type(8))) unsigned short;
using f32x4 = __attribute__((ext_vector_type(4))) float;
using u32x2 = __attribute__((ext_vector_type(2))) unsigned;

#define HALL_TSTRIDE 512
#define HALL_BSTRIDE (80 * 512)

__device__ __forceinline__ unsigned short f2bf(float f) {
  unsigned u = __builtin_bit_cast(unsigned, f);
  u += 0x7fffu + ((u >> 16) & 1u);   // round-to-nearest-even
  return (unsigned short)(u >> 16);
}
__device__ __forceinline__ float bf2f(unsigned short h) {
  unsigned u = ((unsigned)h) << 16;
  return __builtin_bit_cast(float, u);
}
__device__ __forceinline__ float silu(float x) {
  return x / (1.f + __expf(-x));
}
__device__ __forceinline__ float tanh_fast(float x) {
  float e2 = __expf(2.f * x);                    // inf/0 saturate correctly
  return 1.f - 2.f * __builtin_amdgcn_rcpf(e2 + 1.f);
}

// 8 cubic B-spline basis values on the uniform 12-knot grid.
__device__ __forceinline__ void basis8_f32(float xv, float g0, float invh, float* out) {
  float u = (xv - g0) * invh;
  float fs = floorf(u);
  int s = (int)fs;
  float r = u - fs;
  float omr = 1.f - r;
  float r2 = r * r, r3 = r2 * r;
  float n0 = (1.f / 6.f) * omr * omr * omr;
  float n1 = (1.f / 6.f) * (3.f * r3 - 6.f * r2 + 4.f);
  float n2 = (1.f / 6.f) * (-3.f * r3 + 3.f * r2 + 3.f * r + 1.f);
  float n3 = (1.f / 6.f) * r3;
#pragma unroll
  for (int j = 0; j < 8; ++j) {
    int d = s - j;
    out[j] = (d == 0) ? n3 : (d == 1) ? n2 : (d == 2) ? n1 : (d == 3) ? n0 : 0.f;
  }
}

__device__ __forceinline__ u16x8 basis8_bf16(float xv, float g0, float invh) {
  float t[8];
  basis8_f32(xv, g0, invh, t);
  u16x8 o;
#pragma unroll
  for (int j = 0; j < 8; ++j) o[j] = f2bf(t[j]);
  return o;
}

// ---------------------------------------------------------------------------
// Prep kernels
// ---------------------------------------------------------------------------
// Waug2: tiled + swizzled B-panel image for global_load_lds.
__global__ __launch_bounds__(256) void prep_waug2(const float* __restrict__ bw,
                                                  const float* __restrict__ sw,
                                                  const float* __restrict__ sc,
                                                  unsigned short* __restrict__ Waug2) {
  int o = blockIdx.x;
  for (int k = threadIdx.x; k < 2304; k += 256) {
    float v;
    if (k < 256) {
      v = bw[o * 256 + k];
    } else {
      int idx = k - 256;
      int i = idx >> 3, g = idx & 7;
      v = sw[(o * 256 + i) * 8 + g] * sc[o * 256 + i];
    }
    int ks = k >> 6;
    int q = (k >> 3) & 7;
    int p = q ^ (o & 7);
    int e = k & 7;
    Waug2[(long)ks * 32768 + o * 64 + p * 8 + e] = f2bf(v);
  }
}

__global__ __launch_bounds__(256) void prep_whh(const float* __restrict__ w,
                                                unsigned short* __restrict__ hi,
                                                unsigned short* __restrict__ lo) {
  for (int i = blockIdx.x * 256 + threadIdx.x; i < 512 * 512; i += gridDim.x * 256) {
    float v = w[i];
    unsigned short h = f2bf(v);
    hi[i] = h;
    lo[i] = f2bf(v - bf2f(h));
  }
}

// i2h for x==0: parallel (one block per output, coalesced, LDS tree reduce).
__global__ __launch_bounds__(256) void prep_i2hz(const float* __restrict__ sw,
                                                 const float* __restrict__ sc,
                                                 const float* __restrict__ grd,
                                                 float* __restrict__ i2hz,
                                                 unsigned* __restrict__ cnt) {
  __shared__ float red[256];
  const int o = blockIdx.x;
  const int t = threadIdx.x;
  if (o == 0) {
    for (int i = t; i < 64 * 32; i += 256) cnt[i] = 0u;
  }
  float g0 = grd[0];
  float invh = 1.f / (grd[1] - grd[0]);
  float bs[8];
  basis8_f32(0.f, g0, invh, bs);
  const float* swrow = sw + ((long)o * 256 + t) * 8;
  float a = 0.f;
#pragma unroll
  for (int j = 0; j < 8; ++j) a += bs[j] * swrow[j];
  red[t] = a * sc[o * 256 + t];
  __syncthreads();
  for (int w = 128; w > 0; w >>= 1) {
    if (t < w) red[t] += red[t + w];
    __syncthreads();
  }
  if (t == 0) i2hz[o] = red[0];
}

// ---------------------------------------------------------------------------
// Phase A: i2h GEMM.  C(65536 x 512) = A_aug(65536 x 2304) @ W_aug^T.
// 512 blocks x 512 threads; tile 128m x 512n; B via global_load_lds(16) from
// pre-swizzled Waug2; A computed on the fly, swizzle-written.  [R7-proven]
// ---------------------------------------------------------------------------
__global__ __launch_bounds__(512, 2) void kan_i2h_gemm(const float* __restrict__ x,
                                                       const float* __restrict__ grd,
                                                       const unsigned short* __restrict__ Waug2,
                                                       float* __restrict__ hall) {
  __shared__ __align__(128) short Bs[512 * 64];   // 64 KB
  __shared__ __align__(128) short As[128 * 64];   // 16 KB

  const int m0 = blockIdx.x * 128;
  const int tid = threadIdx.x;
  const int lane = tid & 63, wave = tid >> 6;   // 8 waves
  const int wr = wave >> 2, wc = wave & 3;      // 2 x 4
  const int colg = lane & 15, kgrp = lane >> 4;

  float g0 = grd[0];
  float invh = 1.f / (grd[1] - grd[0]);

  f32x4 acc[4][8] = {};

  const int arow = tid >> 2, apart = tid & 3;   // A: 128 rows x 4 parts x 16k
  const float* xrow = x + (long)(m0 + arow) * 256;
  const int aswz = arow & 7;

  for (int ks = 0; ks < 36; ++ks) {
    // ---- B DMA: 64 KB linear copy (content pre-swizzled in Waug2) ----
    {
      const unsigned short* bsrc = Waug2 + (long)ks * 32768 + wave * 512 + lane * 8;
      char* bdst = (char*)Bs + wave * 1024;
#pragma unroll
      for (int i = 0; i < 8; ++i)
        __builtin_amdgcn_global_load_lds(
            (const __attribute__((address_space(1))) unsigned int*)(bsrc + i * 4096),
            (__attribute__((address_space(3))) unsigned int*)(bdst + i * 8192), 16, 0, 0);
    }
    // ---- A compute (16 k per thread) -> swizzled ds_write ----
    {
      int kA = ks * 64 + apart * 16;
      u16x8 d0, d1;
      if (ks < 4) {
        const float* xs = xrow + kA;
        f32x4 v0 = *(const f32x4*)(xs);
        f32x4 v1 = *(const f32x4*)(xs + 4);
        f32x4 v2 = *(const f32x4*)(xs + 8);
        f32x4 v3 = *(const f32x4*)(xs + 12);
#pragma unroll
        for (int e = 0; e < 4; ++e) {
          d0[e] = f2bf(silu(v0[e]));
          d0[e + 4] = f2bf(silu(v1[e]));
          d1[e] = f2bf(silu(v2[e]));
          d1[e + 4] = f2bf(silu(v3[e]));
        }
      } else {
        int i0 = (kA - 256) >> 3;
        d0 = basis8_bf16(xrow[i0], g0, invh);
        d1 = basis8_bf16(xrow[i0 + 1], g0, invh);
      }
      int p0 = (apart * 2) ^ aswz;
      int p1 = (apart * 2 + 1) ^ aswz;
      *(u16x8*)((char*)As + arow * 128 + p0 * 16) = d0;
      *(u16x8*)((char*)As + arow * 128 + p1 * 16) = d1;
    }
    __syncthreads();   // drains gload_lds (vmcnt) + ds_write (lgkm)
#pragma unroll
    for (int kk = 0; kk < 2; ++kk) {
      const int q = kk * 4 + kgrp;
      s16x8 a[4], b[8];
#pragma unroll
      for (int i = 0; i < 4; ++i) {
        int ra = wr * 64 + i * 16 + colg;
        a[i] = *(const s16x8*)((const char*)As + ra * 128 + (q ^ (ra & 7)) * 16);
      }
#pragma unroll
      for (int j = 0; j < 8; ++j) {
        int rb = wc * 128 + j * 16 + colg;
        b[j] = *(const s16x8*)((const char*)Bs + rb * 128 + (q ^ (rb & 7)) * 16);
      }
#pragma unroll
      for (int i = 0; i < 4; ++i)
#pragma unroll
        for (int j = 0; j < 8; ++j)
          acc[i][j] = __builtin_amdgcn_mfma_f32_16x16x32_bf16(a[i], b[j], acc[i][j], 0, 0, 0);
    }
    __syncthreads();
  }

  const int c0 = wc * 128;
#pragma unroll
  for (int i = 0; i < 4; ++i) {
    int mbase = m0 + wr * 64 + i * 16 + (kgrp << 2);
#pragma unroll
    for (int r = 0; r < 4; ++r) {
      int m = mbase + r;
      int bb = m >> 6, tt = m & 63;
      float* orow = hall + (long)bb * HALL_BSTRIDE + (long)tt * HALL_TSTRIDE + c0;
#pragma unroll
      for (int j = 0; j < 8; ++j) orow[j * 16 + colg] = acc[i][j][r];
    }
  }
}

// ---------------------------------------------------------------------------
// Phase B: VGPR-pinned-weight recurrence — EXACT R6/R8 version (400us,
// profiled twice).  256 blocks x 512 threads (1 block/CU), block = 16 batch
// rows x 128 cols, 8 waves x 16 cols, weights pinned via asm loads.
// 4 siblings/group on one XCD.  R9's 4-wave split REGRESSED (sync cost
// scales with participants; lockstep blocks don't interleave) — keep 8-wave.
// ---------------------------------------------------------------------------
__device__ __forceinline__ void pack_write_h(f32x4 v, int rr, int c16,
                                             char* hHb, char* hLb) {
  unsigned h0 = f2bf(v[0]), h1 = f2bf(v[1]), h2 = f2bf(v[2]), h3 = f2bf(v[3]);
  unsigned l0 = f2bf(v[0] - bf2f((unsigned short)h0));
  unsigned l1 = f2bf(v[1] - bf2f((unsigned short)h1));
  unsigned l2 = f2bf(v[2] - bf2f((unsigned short)h2));
  unsigned l3 = f2bf(v[3] - bf2f((unsigned short)h3));
  u32x2 hw, lw;
  hw[0] = h0 | (h1 << 16); hw[1] = h2 | (h3 << 16);
  lw[0] = l0 | (l1 << 16); lw[1] = l2 | (l3 << 16);
  int byte = (rr * 1024 + c16 * 8) ^ ((rr & 7) << 4);
  *(u32x2*)(hHb + byte) = hw;
  *(u32x2*)(hLb + byte) = lw;
}

__global__ __launch_bounds__(512, 2) void rnn_persist(
    const unsigned short* __restrict__ WhhHi,
    const unsigned short* __restrict__ WhhLo,
    const float* __restrict__ i2hz,
    const float* __restrict__ h2hb,
    const float* __restrict__ h0,
    float* __restrict__ hall,
    unsigned* __restrict__ cnt) {
  __shared__ __align__(16) char hHb[16 * 1024];
  __shared__ __align__(16) char hLb[16 * 1024];

  const int tid = threadIdx.x;
  const int lane = tid & 63;
  const int wave = tid >> 6;            // 0..7
  const int bid = blockIdx.x;
  // XCD-local grouping: the 4 col-siblings of a batch-group share bid%8
  const int xcd = bid & 7;              // XCD (round-robin dispatch)
  const int j = bid >> 3;               // 0..31
  const int cg = j & 3;                 // col-group
  const int g = xcd * 8 + (j >> 2);     // batch-group 0..63
  const int m0 = g * 16;                // batch rows
  const int colg = lane & 15;
  const int kgrp = lane >> 4;           // 0..3
  const int o = cg * 128 + wave * 16 + colg;   // this lane's output col
  const int aswz = (colg & 7) << 4;

  // ---- pin this wave's weight slice in VGPRs (asm: not rematerializable) --
  s16x8 wh[16], wl[16];
#pragma unroll
  for (int kk = 0; kk < 16; ++kk) {
    const unsigned short* ph = WhhHi + (long)o * 512 + kk * 32 + kgrp * 8;
    const unsigned short* pl = WhhLo + (long)o * 512 + kk * 32 + kgrp * 8;
    asm volatile("global_load_dwordx4 %0, %1, off" : "=v"(wh[kk]) : "v"(ph));
    asm volatile("global_load_dwordx4 %0, %1, off" : "=v"(wl[kk]) : "v"(pl));
  }
  const float bias = h2hb[o];
  const float i2z = i2hz[o];
  asm volatile("s_waitcnt vmcnt(0)" ::: "memory");
  __builtin_amdgcn_sched_barrier(0);

  // ---- prologue: h0 -> LDS (hi/lo, swizzled) ----
  {
    const int rr = tid >> 5, cc = tid & 31;
#pragma unroll
    for (int jj = 0; jj < 4; ++jj) {
      int c16 = cc + jj * 32;
      f32x4 v = *(const f32x4*)(h0 + (long)(m0 + rr) * 512 + c16 * 4);
      pack_write_h(v, rr, c16, hHb, hLb);
    }
  }
  __syncthreads();

  for (int T = 0; T < 80; ++T) {
    // issue i2h coherent loads early (land under MFMA loop)
    float i2v[4];
    if (T < 64) {
#pragma unroll
      for (int r = 0; r < 4; ++r) {
        const float* p = hall + (long)(m0 + kgrp * 4 + r) * HALL_BSTRIDE +
                         (long)T * HALL_TSTRIDE + o;
        asm volatile("global_load_dword %0, %1, off sc0 sc1" : "=v"(i2v[r]) : "v"(p));
      }
    }

    f32x4 aA = {}, aB = {}, aC = {};
#pragma unroll
    for (int kk = 0; kk < 16; ++kk) {
      int abyte = (colg * 1024 + kk * 64 + kgrp * 16) ^ aswz;
      s16x8 ah = *(const s16x8*)(hHb + abyte);
      s16x8 al = *(const s16x8*)(hLb + abyte);
      aA = __builtin_amdgcn_mfma_f32_16x16x32_bf16(ah, wh[kk], aA, 0, 0, 0);
      aB = __builtin_amdgcn_mfma_f32_16x16x32_bf16(ah, wl[kk], aB, 0, 0, 0);
      aC = __builtin_amdgcn_mfma_f32_16x16x32_bf16(al, wh[kk], aC, 0, 0, 0);
    }

    if (T < 64) {
      asm volatile("s_waitcnt vmcnt(0)" ::: "memory");
      __builtin_amdgcn_sched_barrier(0);
    } else {
#pragma unroll
      for (int r = 0; r < 4; ++r) i2v[r] = i2z;
    }

    // epilogue: tanh + coherent store of h into hall (the exchange medium)
#pragma unroll
    for (int r = 0; r < 4; ++r) {
      float pre = aA[r] + aB[r] + aC[r] + i2v[r] + bias;
      float h = tanh_fast(pre);
      float* p = hall + (long)(m0 + kgrp * 4 + r) * HALL_BSTRIDE +
                 (long)T * HALL_TSTRIDE + o;
      asm volatile("global_store_dword %0, %1, off sc0 sc1" :: "v"(p), "v"(h) : "memory");
    }

    if (T == 79) break;

    asm volatile("s_waitcnt vmcnt(0)" ::: "memory");
    __syncthreads();                       // all waves' stores complete
    if (tid == 0) {
      __hip_atomic_fetch_add(&cnt[g * 32], 1u, __ATOMIC_RELEASE,
                             __HIP_MEMORY_SCOPE_AGENT);
      unsigned tgt = 4u * (unsigned)(T + 1);
      while (__hip_atomic_load(&cnt[g * 32], __ATOMIC_RELAXED,
                               __HIP_MEMORY_SCOPE_AGENT) < tgt)
        __builtin_amdgcn_s_sleep(2);
    }
    __syncthreads();

    // A-refill: coherent loads of h_T (16 rows x 512) -> LDS hi/lo
    {
      const int rr = tid >> 5, cc = tid & 31;
      const float* src = hall + (long)(m0 + rr) * HALL_BSTRIDE + (long)T * HALL_TSTRIDE;
      f32x4 v[4];
#pragma unroll
      for (int jj = 0; jj < 4; ++jj) {
        const float* p = src + (cc + jj * 32) * 4;
        asm volatile("global_load_dwordx4 %0, %1, off sc0 sc1" : "=v"(v[jj]) : "v"(p));
      }
      asm volatile("s_waitcnt vmcnt(0)" ::: "memory");
      __builtin_amdgcn_sched_barrier(0);
#pragma unroll
      for (int jj = 0; jj < 4; ++jj) pack_write_h(v[jj], rr, cc + jj * 32, hHb, hLb);
    }
    __syncthreads();
  }
}

// ---------------------------------------------------------------------------
// y_pred[b][ty] = dot(h_all[b][64+ty][:], fc_w) + fc_b   (one wave per (b,ty))
// ---------------------------------------------------------------------------
__global__ __launch_bounds__(256) void y_final(const float* __restrict__ hall,
                                               const float* __restrict__ fcw,
                                               const float* __restrict__ fcb,
                                               float* __restrict__ y) {
  int gw = (blockIdx.x * 256 + threadIdx.x) >> 6;
  int lane = threadIdx.x & 63;
  int bb = gw >> 4, ty = gw & 15;
  const float* hrow = hall + (long)bb * HALL_BSTRIDE + (long)(64 + ty) * HALL_TSTRIDE;
  float s = 0.f;
#pragma unroll
  for (int c = 0; c < 8; ++c) s += hrow[lane + c * 64] * fcw[lane + c * 64];
#pragma unroll
  for (int off = 32; off > 0; off >>= 1) s += __shfl_xor(s, off);
  if (lane == 0) y[bb * 16 + ty] = s + fcb[0];
}

// ---------------------------------------------------------------------------
extern "C" void kernel_launch(void* const* d_in, const int* in_sizes, int n_in,
                              void* d_out, int out_size, void* d_ws, size_t ws_size,
                              hipStream_t stream) {
  (void)in_sizes; (void)n_in; (void)out_size; (void)ws_size;
  const float* x   = (const float*)d_in[0];
  const float* h0  = (const float*)d_in[1];
  const float* grd = (const float*)d_in[2];
  const float* bw  = (const float*)d_in[3];
  const float* sw  = (const float*)d_in[4];
  const float* sc  = (const float*)d_in[5];
  const float* whh = (const float*)d_in[6];
  const float* hbb = (const float*)d_in[7];
  const float* fcw = (const float*)d_in[8];
  const float* fcb = (const float*)d_in[9];

  float* out = (float*)d_out;
  float* ypred = out;
  float* hall = out + 1024 * 16;

  char* ws = (char*)d_ws;
  unsigned short* Waug2 = (unsigned short*)(ws);                 // 2359296 B
  unsigned short* WhhHi = (unsigned short*)(ws + 2359296);       // 524288 B
  unsigned short* WhhLo = (unsigned short*)(ws + 2883584);       // 524288 B
  float*          i2hz  = (float*)(ws + 3407872);                // 2048 B
  unsigned*       cnt   = (unsigned*)(ws + 3409920);             // 8192 B

  prep_waug2<<<512, 256, 0, stream>>>(bw, sw, sc, Waug2);
  prep_whh<<<512, 256, 0, stream>>>(whh, WhhHi, WhhLo);
  prep_i2hz<<<512, 256, 0, stream>>>(sw, sc, grd, i2hz, cnt);
  kan_i2h_gemm<<<512, 512, 0, stream>>>(x, grd, Waug2, hall);
  rnn_persist<<<256, 512, 0, stream>>>(WhhHi, WhhLo, i2hz, hbb, h0, hall, cnt);
  y_final<<<4096, 256, 0, stream>>>(hall, fcw, fcb, ypred);
}